// Round 16
// baseline (45.762 us; speedup 1.0000x reference)
//
#include <hip/hip_runtime.h>

#define N_IN   4096
#define N_NPB  64
#define COLS   16384
#define BATCH  128

typedef unsigned int       uint;
typedef unsigned short     ushort;
typedef unsigned char      uchar;
typedef unsigned long long u64;

// ---------------------------------------------------------------------------
// ws layout:
//   [0,      512 K)   x8  : u8 xT[4096][128], val = rint(x*127/s_i)+128
//   [512 K,  528 K)   scl : f32[4096] = s_i/127   (s_i = max_b |x[b,i]|)
//   [1 MiB, 1 MiB+128K) keep: ushort[COLS][4] = 64-bit keep mask per column
// ---------------------------------------------------------------------------

// keepmask helper: bit j (of this 16-k group) = 1 iff no later k' duplicates.
template <int KBASE>
static __device__ __forceinline__ uint compute_bits(const int* __restrict__ ip) {
  int v[64 - KBASE];
#pragma unroll
  for (int k = 0; k < 64 - KBASE; ++k) v[k] = ip[(KBASE + k) * COLS];
  uint bits = 0;
#pragma unroll
  for (int j = 0; j < 16; ++j) {
    uint m = 0xffffffffu;
#pragma unroll
    for (int kp = j + 1; kp < 64 - KBASE; ++kp)
      m = min(m, (uint)(v[j] ^ v[kp]));
    bits |= (m != 0u) ? (1u << j) : 0u;
  }
  return bits;
}

// Prep: blocks [0,128) = per-feature scale + int8 quant + transpose;
//       blocks [128,384) = keepmask.
__global__ __launch_bounds__(256, 4) void prep_kernel(
    const float* __restrict__ x, const int* __restrict__ idx,
    uchar* __restrict__ x8, float* __restrict__ scl,
    ushort* __restrict__ keep16) {
  const int bid = blockIdx.x;
  const int tid = threadIdx.x;
  if (bid < 128) {
    __shared__ float tile[128][33];   // [batch][feature-of-32]
    __shared__ float pmax[8][32];
    __shared__ float sinv[32];
    __shared__ uint  qrow[32][32];    // [feature][batch-quad] packed u8x4

    const int i0 = bid * 32;
    const int f  = tid & 31;
    const int g  = tid >> 5;          // 0..7

    // load 32 features x 128 batches (coalesced 128 B per 32-lane group)
#pragma unroll
    for (int p = 0; p < 16; ++p) {
      const int b = p * 8 + g;
      tile[b][f] = x[b * N_IN + i0 + f];
    }
    __syncthreads();

    // per-feature max |x| (8 partials x 16 batches, then reduce)
    {
      float m = 0.0f;
      const int b0 = g * 16;
#pragma unroll
      for (int j = 0; j < 16; ++j) m = fmaxf(m, fabsf(tile[b0 + j][f]));
      pmax[g][f] = m;
    }
    __syncthreads();
    if (tid < 32) {
      float m = pmax[0][tid];
#pragma unroll
      for (int p = 1; p < 8; ++p) m = fmaxf(m, pmax[p][tid]);
      m = fmaxf(m, 1e-30f);
      scl[i0 + tid]  = m * (1.0f / 127.0f);
      sinv[tid] = 127.0f / m;
    }
    __syncthreads();

    // quantize: u8 = clamp(rint(x*127/s), -127, 127) + 128
    {
      const float iv = sinv[f];
#pragma unroll
      for (int p = 0; p < 4; ++p) {
        const int bq = g + p * 8;     // 0..31
        uint pk4 = 0;
#pragma unroll
        for (int j = 0; j < 4; ++j) {
          float q = rintf(tile[bq * 4 + j][f] * iv);
          q = fminf(fmaxf(q, -127.0f), 127.0f);
          pk4 |= ((uint)(q + 128.0f)) << (8 * j);
        }
        qrow[f][bq] = pk4;
      }
    }
    __syncthreads();

    // write rows coalesced: feature row = 128 B = 32 dwords
    for (int e = tid; e < 32 * 32; e += 256) {
      const int ff = e >> 5, d = e & 31;
      ((uint*)x8)[(i0 + ff) * 32 + d] = qrow[ff][d];
    }
  } else {
    const int kg = __builtin_amdgcn_readfirstlane(tid >> 6);  // wave-uniform
    const int c  = (bid - 128) * 64 + (tid & 63);
    const int* ip = idx + c;
    uint bits;
    if      (kg == 0) bits = compute_bits<0>(ip);
    else if (kg == 1) bits = compute_bits<16>(ip);
    else if (kg == 2) bits = compute_bits<32>(ip);
    else              bits = compute_bits<48>(ip);
    keep16[c * 4 + kg] = (ushort)bits;
  }
}

// ---------------------------------------------------------------------------
// Main: out[b,c] = sum_k w'_k*(u8 - 128), w' = w_eff * s_row/127.
// u8 rows are 128 B = ONE cache line (vs f16's two) -> half the line services.
// 512 thr = 8 waves; waves 0-3 k=0..31, 4-7 k=32..63 (split-k via res).
// Lane = (ksub=lane>>5, cslot=(lane>>3)&3, bl=lane&7): per wave-instr,
// 8 (k,c) pairs x 16 batches/lane (dwordx4 = 16 u8 = full row per 8 lanes).
// ksub halves combined via __shfl_xor(32) [R15's dup-write bug fixed];
// -128 offset folded into per-column bias carried through res slot 128.
// ---------------------------------------------------------------------------
__global__ __launch_bounds__(512, 8) void branch_main_kernel(
    const float* __restrict__ w, const int* __restrict__ idx,
    const u64* __restrict__ keep, const uchar* __restrict__ x8,
    const float* __restrict__ scl, float* __restrict__ out) {
  __shared__ u64   pk[N_NPB][16];     // hi32 = f32 w' bits, lo32 = row*128
  __shared__ float res[2][16][132];   // [khalf][col][0..127 batches, 128=wsum]

  const int tid = threadIdx.x;
  const int c0  = blockIdx.x * 16;

  // Stage packed entries; 2 per thread, coalesced. scl gather is L1-hot (16K).
  {
    const int cl = tid & 15;
    const int k0 = (tid >> 4) * 2;
    const u64 km = keep[c0 + cl];
#pragma unroll
    for (int p = 0; p < 2; ++p) {
      const int k   = k0 + p;
      const int row = idx[k * COLS + c0 + cl];
      float wv      = w[k * COLS + c0 + cl];
      wv = ((km >> k) & 1ull) ? wv * scl[row] : 0.0f;
      pk[k][cl] = ((u64)__builtin_bit_cast(uint, wv) << 32) |
                  ((u64)((uint)row << 7));
    }
  }
  __syncthreads();

  const int wave  = tid >> 6;
  const int khalf = wave >> 2;
  const int lane  = tid & 63;
  const int ksub  = lane >> 5;        // 0: even kk, 1: odd kk
  const int cslot = (lane >> 3) & 3;
  const int bl    = lane & 7;         // batches [bl*16, bl*16+16)
  const int cl    = (wave & 3) * 4 + cslot;
  const int kb    = khalf * 32;

  const char* xb = (const char*)x8;
  const uint  bo = (uint)bl * 16;

  float acc[16];
#pragma unroll
  for (int j = 0; j < 16; ++j) acc[j] = 0.0f;
  float wsum = 0.0f;

#pragma unroll
  for (int kk = 0; kk < 32; kk += 2) {
    const u64  e   = pk[kb + kk + ksub][cl];      // ds_read_b64, 8-way bcast
    const uint off = (uint)e + bo;
    const float wv = __builtin_bit_cast(float, (uint)(e >> 32));
    const uint4 u  = *(const uint4*)(xb + off);   // 16 u8 batches (ONE line)
    wsum += wv;
#define DEC(word, sh) ((float)((word >> sh) & 0xffu))   /* v_cvt_f32_ubyteN */
    acc[0]  = fmaf(wv, DEC(u.x, 0),  acc[0]);
    acc[1]  = fmaf(wv, DEC(u.x, 8),  acc[1]);
    acc[2]  = fmaf(wv, DEC(u.x, 16), acc[2]);
    acc[3]  = fmaf(wv, DEC(u.x, 24), acc[3]);
    acc[4]  = fmaf(wv, DEC(u.y, 0),  acc[4]);
    acc[5]  = fmaf(wv, DEC(u.y, 8),  acc[5]);
    acc[6]  = fmaf(wv, DEC(u.y, 16), acc[6]);
    acc[7]  = fmaf(wv, DEC(u.y, 24), acc[7]);
    acc[8]  = fmaf(wv, DEC(u.z, 0),  acc[8]);
    acc[9]  = fmaf(wv, DEC(u.z, 8),  acc[9]);
    acc[10] = fmaf(wv, DEC(u.z, 16), acc[10]);
    acc[11] = fmaf(wv, DEC(u.z, 24), acc[11]);
    acc[12] = fmaf(wv, DEC(u.w, 0),  acc[12]);
    acc[13] = fmaf(wv, DEC(u.w, 8),  acc[13]);
    acc[14] = fmaf(wv, DEC(u.w, 16), acc[14]);
    acc[15] = fmaf(wv, DEC(u.w, 24), acc[15]);
#undef DEC
  }

  // Combine ksub halves (partner = lane^32); lanes<32 hold the full khalf sum.
#pragma unroll
  for (int j = 0; j < 16; ++j) acc[j] += __shfl_xor(acc[j], 32);
  wsum += __shfl_xor(wsum, 32);

  if (lane < 32) {
    float* r = &res[khalf][cl][bl * 16];
#pragma unroll
    for (int j = 0; j < 16; ++j) r[j] = acc[j];
    if (bl == 0) res[khalf][cl][128] = wsum;
  }
  __syncthreads();

  // Combine split-k + subtract 128*sum(w') bias; coalesced output.
  for (int e = tid; e < BATCH * 16; e += 512) {
    const int b = e >> 4, cc = e & 15;
    const float bias = 128.0f * (res[0][cc][128] + res[1][cc][128]);
    out[b * COLS + c0 + cc] = res[0][cc][b] + res[1][cc][b] - bias;
  }
}

extern "C" void kernel_launch(void* const* d_in, const int* in_sizes, int n_in,
                              void* d_out, int out_size, void* d_ws, size_t ws_size,
                              hipStream_t stream) {
  const float* x   = (const float*)d_in[0];
  const float* w   = (const float*)d_in[1];
  const int*   idx = (const int*)d_in[2];
  float* out = (float*)d_out;

  char* ws = (char*)d_ws;
  uchar*  x8     = (uchar*)(ws);
  float*  scl    = (float*)(ws + (512u << 10));
  ushort* keep16 = (ushort*)(ws + (1u << 20));
  u64*    keep   = (u64*)(ws + (1u << 20));

  hipLaunchKernelGGL(prep_kernel, dim3(128 + COLS / 64), dim3(256), 0, stream,
                     x, idx, x8, scl, keep16);
  hipLaunchKernelGGL(branch_main_kernel, dim3(COLS / 16), dim3(512), 0, stream,
                     w, idx, keep, x8, scl, out);
}

// Round 17
// 44.938 us; speedup vs baseline: 1.0183x; 1.0183x over previous
//
#include <hip/hip_runtime.h>

#define N_IN   4096
#define N_NPB  64
#define COLS   16384
#define BATCH  128

typedef unsigned int       uint;
typedef unsigned short     ushort;
typedef unsigned char      uchar;
typedef unsigned long long u64;

// ---------------------------------------------------------------------------
// ws layout:
//   [0,      512 K)     x8  : u8 xT[4096][128], val = rint(x*127/s_i)+128
//   [512 K,  528 K)     scl : f32[4096] = s_i/127  (s_i = max_b |x[b,i]|)
//   [1 MiB, 1 MiB+128K) keep: ushort[COLS][4] = 64-bit keep mask per column
// ---------------------------------------------------------------------------

// keepmask helper: bit j (of this 16-k group) = 1 iff no later k' duplicates.
template <int KBASE>
static __device__ __forceinline__ uint compute_bits(const int* __restrict__ ip) {
  int v[64 - KBASE];
#pragma unroll
  for (int k = 0; k < 64 - KBASE; ++k) v[k] = ip[(KBASE + k) * COLS];
  uint bits = 0;
#pragma unroll
  for (int j = 0; j < 16; ++j) {
    uint m = 0xffffffffu;
#pragma unroll
    for (int kp = j + 1; kp < 64 - KBASE; ++kp)
      m = min(m, (uint)(v[j] ^ v[kp]));
    bits |= (m != 0u) ? (1u << j) : 0u;
  }
  return bits;
}

// Prep: blocks [0,128) = per-feature scale + int8 quant + transpose;
//       blocks [128,384) = keepmask.  (Verified in R16: absmax 0.0039.)
__global__ __launch_bounds__(256, 4) void prep_kernel(
    const float* __restrict__ x, const int* __restrict__ idx,
    uchar* __restrict__ x8, float* __restrict__ scl,
    ushort* __restrict__ keep16) {
  const int bid = blockIdx.x;
  const int tid = threadIdx.x;
  if (bid < 128) {
    __shared__ float tile[128][33];   // [batch][feature-of-32]
    __shared__ float pmax[8][32];
    __shared__ float sinv[32];
    __shared__ uint  qrow[32][32];    // [feature][batch-quad] packed u8x4

    const int i0 = bid * 32;
    const int f  = tid & 31;
    const int g  = tid >> 5;          // 0..7

#pragma unroll
    for (int p = 0; p < 16; ++p) {
      const int b = p * 8 + g;
      tile[b][f] = x[b * N_IN + i0 + f];
    }
    __syncthreads();

    {
      float m = 0.0f;
      const int b0 = g * 16;
#pragma unroll
      for (int j = 0; j < 16; ++j) m = fmaxf(m, fabsf(tile[b0 + j][f]));
      pmax[g][f] = m;
    }
    __syncthreads();
    if (tid < 32) {
      float m = pmax[0][tid];
#pragma unroll
      for (int p = 1; p < 8; ++p) m = fmaxf(m, pmax[p][tid]);
      m = fmaxf(m, 1e-30f);
      scl[i0 + tid] = m * (1.0f / 127.0f);
      sinv[tid] = 127.0f / m;
    }
    __syncthreads();

    {
      const float iv = sinv[f];
#pragma unroll
      for (int p = 0; p < 4; ++p) {
        const int bq = g + p * 8;     // 0..31
        uint pk4 = 0;
#pragma unroll
        for (int j = 0; j < 4; ++j) {
          float q = rintf(tile[bq * 4 + j][f] * iv);
          q = fminf(fmaxf(q, -127.0f), 127.0f);
          pk4 |= ((uint)(q + 128.0f)) << (8 * j);
        }
        qrow[f][bq] = pk4;
      }
    }
    __syncthreads();

    for (int e = tid; e < 32 * 32; e += 256) {
      const int ff = e >> 5, d = e & 31;
      ((uint*)x8)[(i0 + ff) * 32 + d] = qrow[ff][d];
    }
  } else {
    const int kg = __builtin_amdgcn_readfirstlane(tid >> 6);  // wave-uniform
    const int c  = (bid - 128) * 64 + (tid & 63);
    const int* ip = idx + c;
    uint bits;
    if      (kg == 0) bits = compute_bits<0>(ip);
    else if (kg == 1) bits = compute_bits<16>(ip);
    else if (kg == 2) bits = compute_bits<32>(ip);
    else              bits = compute_bits<48>(ip);
    keep16[c * 4 + kg] = (ushort)bits;
  }
}

// ---------------------------------------------------------------------------
// Main: out[b,c] = sum_k w'_k*(u8-128), w' = w_eff*s_row/127.
// EXACT R6 geometry (verified 23.8 us), only the row payload changes:
// u8 rows = 128 B = ONE line; lane loads dwordx2 (8 B = 8 batches), 16
// lanes/row, 4 rows per wave-instr, 262K wave-instrs total (unchanged).
// Split-k: waves 0-3 k=0..31, waves 4-7 k=32..63; res-combine at end.
// -128 offset folded into per-column bias (wsum) carried via res slot 128.
// ---------------------------------------------------------------------------
__global__ __launch_bounds__(512, 8) void branch_main_kernel(
    const float* __restrict__ w, const int* __restrict__ idx,
    const u64* __restrict__ keep, const uchar* __restrict__ x8,
    const float* __restrict__ scl, float* __restrict__ out) {
  __shared__ u64   pk[N_NPB][16];     // hi32 = f32 w' bits, lo32 = row*128
  __shared__ float res[2][16][132];   // [khalf][col][0..127 batch, 128 = wsum]

  const int tid = threadIdx.x;
  const int c0  = blockIdx.x * 16;

  // Stage packed entries; 2 per thread, coalesced. scl gather is L2-hot (16K).
  {
    const int cl = tid & 15;
    const int k0 = (tid >> 4) * 2;
    const u64 km = keep[c0 + cl];
#pragma unroll
    for (int p = 0; p < 2; ++p) {
      const int k   = k0 + p;
      const int row = idx[k * COLS + c0 + cl];
      float wv      = w[k * COLS + c0 + cl];
      wv = ((km >> k) & 1ull) ? wv * scl[row] : 0.0f;
      pk[k][cl] = ((u64)__builtin_bit_cast(uint, wv) << 32) |
                  ((u64)((uint)row << 7));
    }
  }
  __syncthreads();

  const int wave  = tid >> 6;
  const int khalf = wave >> 2;        // 0: k=0..31, 1: k=32..63
  const int lane  = tid & 63;
  const int g     = lane >> 4;        // column of 4
  const int b8    = lane & 15;        // batch octet: [b8*8, b8*8+8)
  const int cl    = (wave & 3) * 4 + g;
  const int kb    = khalf * 32;

  const char* xb = (const char*)x8;
  const uint  bo = (uint)b8 * 8;

  float a0 = 0.f, a1 = 0.f, a2 = 0.f, a3 = 0.f;
  float a4 = 0.f, a5 = 0.f, a6 = 0.f, a7 = 0.f;
  float wsum = 0.0f;

#pragma unroll
  for (int kk = 0; kk < 32; ++kk) {
    const u64  e   = pk[kb + kk][cl];             // ds_read_b64, broadcast
    const uint off = (uint)e + bo;                // one v_add_u32
    const float wv = __builtin_bit_cast(float, (uint)(e >> 32));
    const uint2 u  = *(const uint2*)(xb + off);   // 8 u8 batches (dwordx2)
    wsum += wv;
#define DEC(word, sh) ((float)((word >> sh) & 0xffu))   /* v_cvt_f32_ubyteN */
    a0 = fmaf(wv, DEC(u.x, 0),  a0);
    a1 = fmaf(wv, DEC(u.x, 8),  a1);
    a2 = fmaf(wv, DEC(u.x, 16), a2);
    a3 = fmaf(wv, DEC(u.x, 24), a3);
    a4 = fmaf(wv, DEC(u.y, 0),  a4);
    a5 = fmaf(wv, DEC(u.y, 8),  a5);
    a6 = fmaf(wv, DEC(u.y, 16), a6);
    a7 = fmaf(wv, DEC(u.y, 24), a7);
#undef DEC
  }

  // Stage partials: 8 consecutive floats per lane -> 2x ds_write_b128.
  {
    float* r = &res[khalf][cl][b8 * 8];
    r[0] = a0; r[1] = a1; r[2] = a2; r[3] = a3;
    r[4] = a4; r[5] = a5; r[6] = a6; r[7] = a7;
    if (b8 == 0) res[khalf][cl][128] = wsum;
  }
  __syncthreads();

  // Combine split-k partials, subtract 128*sum(w') bias; coalesced output.
  for (int e = tid; e < BATCH * 16; e += 512) {
    const int b = e >> 4, cc = e & 15;
    const float bias = 128.0f * (res[0][cc][128] + res[1][cc][128]);
    out[b * COLS + c0 + cc] = res[0][cc][b] + res[1][cc][b] - bias;
  }
}

extern "C" void kernel_launch(void* const* d_in, const int* in_sizes, int n_in,
                              void* d_out, int out_size, void* d_ws, size_t ws_size,
                              hipStream_t stream) {
  const float* x   = (const float*)d_in[0];
  const float* w   = (const float*)d_in[1];
  const int*   idx = (const int*)d_in[2];
  float* out = (float*)d_out;

  char* ws = (char*)d_ws;
  uchar*  x8     = (uchar*)(ws);
  float*  scl    = (float*)(ws + (512u << 10));
  ushort* keep16 = (ushort*)(ws + (1u << 20));
  u64*    keep   = (u64*)(ws + (1u << 20));

  hipLaunchKernelGGL(prep_kernel, dim3(128 + COLS / 64), dim3(256), 0, stream,
                     x, idx, x8, scl, keep16);
  hipLaunchKernelGGL(branch_main_kernel, dim3(COLS / 16), dim3(512), 0, stream,
                     w, idx, keep, x8, scl, out);
}

// Round 18
// 23.962 us; speedup vs baseline: 1.9098x; 1.8754x over previous
//
#include <hip/hip_runtime.h>

#define N_IN   4096
#define N_NPB  64
#define COLS   16384
#define BATCH  128

typedef unsigned int       uint;
typedef unsigned short     ushort;
typedef unsigned long long u64;
typedef __attribute__((ext_vector_type(2))) _Float16 h2;

// ---------------------------------------------------------------------------
// ws layout:
//   [0,      1 MiB)       xTh  : f16 xT[4096][128] (ushort)
//   [1 MiB,  1 MiB+128 K) keep : ushort[COLS][4] = 64-bit keep mask per column
// ---------------------------------------------------------------------------

// keepmask helper: bit j (of this 16-k group) = 1 iff no later k' duplicates.
template <int KBASE>
static __device__ __forceinline__ uint compute_bits(const int* __restrict__ ip) {
  int v[64 - KBASE];
#pragma unroll
  for (int k = 0; k < 64 - KBASE; ++k) v[k] = ip[(KBASE + k) * COLS];
  uint bits = 0;
#pragma unroll
  for (int j = 0; j < 16; ++j) {
    uint m = 0xffffffffu;
#pragma unroll
    for (int kp = j + 1; kp < 64 - KBASE; ++kp)
      m = min(m, (uint)(v[j] ^ v[kp]));
    bits |= (m != 0u) ? (1u << j) : 0u;
  }
  return bits;
}

// Fused prep: blocks [0,512) transpose x -> f16 xT; blocks [512,768) keepmask.
__global__ __launch_bounds__(256, 4) void prep_kernel(
    const float* __restrict__ x, const int* __restrict__ idx,
    ushort* __restrict__ xTh, ushort* __restrict__ keep16) {
  const int bid = blockIdx.x;
  const int tid = threadIdx.x;
  if (bid < 512) {
    __shared__ float tile[32][33];
    const int i0 = (bid & 127) * 32;
    const int b0 = (bid >> 7) * 32;
    const int tx = tid & 31;
    const int ty = tid >> 5;    // 0..7
#pragma unroll
    for (int j = 0; j < 32; j += 8)
      tile[ty + j][tx] = x[(b0 + ty + j) * N_IN + i0 + tx];
    __syncthreads();
#pragma unroll
    for (int j = 0; j < 32; j += 8)
      xTh[(i0 + ty + j) * BATCH + b0 + tx] =
          __builtin_bit_cast(ushort, (_Float16)tile[tx][ty + j]);
  } else {
    const int kg = __builtin_amdgcn_readfirstlane(tid >> 6);  // wave-uniform
    const int c  = (bid - 512) * 64 + (tid & 63);
    const int* ip = idx + c;
    uint bits;
    if      (kg == 0) bits = compute_bits<0>(ip);
    else if (kg == 1) bits = compute_bits<16>(ip);
    else if (kg == 2) bits = compute_bits<32>(ip);
    else              bits = compute_bits<48>(ip);
    keep16[c * 4 + kg] = (ushort)bits;
  }
}

// ---------------------------------------------------------------------------
// Main: out[b,c] = sum_k wk * xTh[idx[k][c]][b]
// Split-k: 512 threads = 8 waves. Waves 0-3 do k=0..31, waves 4-7 k=32..63,
// both for the block's 16 columns; partials combined in LDS at the end.
// Within a wave-quad: g=lane>>4 (column of 4), b8=lane&15 (batch octet,
// one dwordx4 = 8 f16 batches -> full 256 B row per 16-lane group).
// Grid 1024 -> 4 blocks/CU x 8 waves = 32 waves/CU (full occupancy).
// ---------------------------------------------------------------------------
__global__ __launch_bounds__(512, 8) void branch_main_kernel(
    const float* __restrict__ w, const int* __restrict__ idx,
    const u64* __restrict__ keep, const ushort* __restrict__ xTh,
    float* __restrict__ out) {
  __shared__ u64   pk[N_NPB][16];
  __shared__ float res[2][16][132];   // [khalf][col][batch], 132: 16B-aligned rows

  const int tid = threadIdx.x;
  const int c0  = blockIdx.x * 16;

  // Stage packed (offset | dup'd f16 weight) entries; 2 per thread, coalesced.
  {
    const int cl = tid & 15;
    const int k0 = (tid >> 4) * 2;
    const u64 km = keep[c0 + cl];
#pragma unroll
    for (int p = 0; p < 2; ++p) {
      const int k   = k0 + p;
      const int row = idx[k * COLS + c0 + cl];
      float wv      = w[k * COLS + c0 + cl];
      wv = ((km >> k) & 1ull) ? wv : 0.0f;
      const uint hb = (uint)__builtin_bit_cast(ushort, (_Float16)wv);
      pk[k][cl] = ((u64)((hb << 16) | hb) << 32) | ((u64)((uint)row << 8));
    }
  }
  __syncthreads();

  const int wave  = tid >> 6;
  const int khalf = wave >> 2;        // 0: k=0..31, 1: k=32..63
  const int lane  = tid & 63;
  const int g     = lane >> 4;
  const int b8    = lane & 15;
  const int cl    = (wave & 3) * 4 + g;

  const char* xb = (const char*)xTh;
  const uint  bo = (uint)b8 * 16;
  const int   kb = khalf * 32;

  h2 a0 = (h2)0.0f, a1 = (h2)0.0f, a2 = (h2)0.0f, a3 = (h2)0.0f;
#pragma unroll
  for (int kk = 0; kk < 32; ++kk) {
    const u64  e   = pk[kb + kk][cl];                 // ds_read_b64, broadcast
    const uint off = (uint)e + bo;                    // one v_add_u32
    const h2   wh  = __builtin_bit_cast(h2, (uint)(e >> 32));
    const uint4 u  = *(const uint4*)(xb + off);       // 8 f16 batches
    a0 += __builtin_bit_cast(h2, u.x) * wh;           // v_pk_fma_f16
    a1 += __builtin_bit_cast(h2, u.y) * wh;
    a2 += __builtin_bit_cast(h2, u.z) * wh;
    a3 += __builtin_bit_cast(h2, u.w) * wh;
  }

  // Stage partials: 8 consecutive floats per lane -> 2x ds_write_b128.
  {
    float* r = &res[khalf][cl][b8 * 8];
    r[0] = (float)a0.x; r[1] = (float)a0.y;
    r[2] = (float)a1.x; r[3] = (float)a1.y;
    r[4] = (float)a2.x; r[5] = (float)a2.y;
    r[6] = (float)a3.x; r[7] = (float)a3.y;
  }
  __syncthreads();

  // Combine split-k partials + coalesced output.
  for (int e = tid; e < BATCH * 16; e += 512) {
    const int b = e >> 4, cc = e & 15;
    out[b * COLS + c0 + cc] = res[0][cc][b] + res[1][cc][b];
  }
}

extern "C" void kernel_launch(void* const* d_in, const int* in_sizes, int n_in,
                              void* d_out, int out_size, void* d_ws, size_t ws_size,
                              hipStream_t stream) {
  const float* x   = (const float*)d_in[0];
  const float* w   = (const float*)d_in[1];
  const int*   idx = (const int*)d_in[2];
  float* out = (float*)d_out;

  char* ws = (char*)d_ws;
  ushort* xTh    = (ushort*)(ws);
  ushort* keep16 = (ushort*)(ws + (1u << 20));
  u64*    keep   = (u64*)(ws + (1u << 20));

  hipLaunchKernelGGL(prep_kernel, dim3(512 + COLS / 64), dim3(256), 0, stream,
                     x, idx, xTh, keep16);
  hipLaunchKernelGGL(branch_main_kernel, dim3(COLS / 16), dim3(512), 0, stream,
                     w, idx, keep, xTh, out);
}